// Round 1
// 602.768 us; speedup vs baseline: 1.5515x; 1.5515x over previous
//
#include <hip/hip_runtime.h>

// ---------------- problem constants ----------------
#define T_SEQ 4096
#define BATCH 4
#define NH 16
#define M_ROWS 16384

typedef __attribute__((ext_vector_type(8))) short short8;
typedef __attribute__((ext_vector_type(4))) float floatx4;

__device__ __forceinline__ float b2f(unsigned short u) {
    union { unsigned int i; float f; } x; x.i = ((unsigned int)u) << 16; return x.f;
}
__device__ __forceinline__ unsigned short f2b(float f) {
    union { float f; unsigned int i; } x; x.f = f;
    unsigned int u = x.i;
    u += 0x7fffu + ((u >> 16) & 1u);   // RNE
    return (unsigned short)(u >> 16);
}

__device__ __forceinline__ void store_out(float* p, float v) { *p = v; }
__device__ __forceinline__ void store_out(unsigned short* p, float v) { *p = f2b(v); }

// load 16 contiguous elements as bf16 (convert when source is f32)
__device__ __forceinline__ void ldconv16(const float* p, uint4& lo, uint4& hi) {
    float4 f0 = *(const float4*)(p);
    float4 f1 = *(const float4*)(p + 4);
    float4 f2 = *(const float4*)(p + 8);
    float4 f3 = *(const float4*)(p + 12);
    unsigned short u[16];
    u[0] = f2b(f0.x); u[1] = f2b(f0.y); u[2]  = f2b(f0.z); u[3]  = f2b(f0.w);
    u[4] = f2b(f1.x); u[5] = f2b(f1.y); u[6]  = f2b(f1.z); u[7]  = f2b(f1.w);
    u[8] = f2b(f2.x); u[9] = f2b(f2.y); u[10] = f2b(f2.z); u[11] = f2b(f2.w);
    u[12] = f2b(f3.x); u[13] = f2b(f3.y); u[14] = f2b(f3.z); u[15] = f2b(f3.w);
    lo = *(uint4*)u; hi = *(uint4*)(u + 8);
}
__device__ __forceinline__ void ldconv16(const unsigned short* p, uint4& lo, uint4& hi) {
    lo = *(const uint4*)p; hi = *(const uint4*)(p + 8);
}

// ---------------- weight transpose+convert: W[K][N] f32 -> Wt[N][K] bf16 ----------------
__global__ __launch_bounds__(256) void transpose_w(
    const float* __restrict__ wq,
    const float* __restrict__ wkv,
    const float* __restrict__ wout,
    unsigned short* __restrict__ wqT,
    unsigned short* __restrict__ wkvT,
    unsigned short* __restrict__ woutT)
{
    int bid = blockIdx.x;
    const float* src; unsigned short* dst; int Nd; int local;
    if (bid < 1024)      { src = wq;   dst = wqT;   Nd = 1024; local = bid; }
    else if (bid < 3072) { src = wkv;  dst = wkvT;  Nd = 2048; local = bid - 1024; }
    else                 { src = wout; dst = woutT; Nd = 1024; local = bid - 3072; }
    int tilesN = Nd >> 5;
    int tk = local / tilesN, tn = local % tilesN;
    __shared__ __align__(16) unsigned short tile[32][36];
    int tid = threadIdx.x;
    int r = tid >> 3, c = (tid & 7) * 4;
    float4 in = *(const float4*)(src + (long)(tk * 32 + r) * Nd + tn * 32 + c);
    tile[r][c] = f2b(in.x); tile[r][c + 1] = f2b(in.y);
    tile[r][c + 2] = f2b(in.z); tile[r][c + 3] = f2b(in.w);
    __syncthreads();
    ushort4 o;
    o.x = tile[c][r]; o.y = tile[c + 1][r]; o.z = tile[c + 2][r]; o.w = tile[c + 3][r];
    *(ushort4*)(dst + (long)(tn * 32 + r) * 1024 + tk * 32 + c) = o;
}

// ---------------- bf16 MFMA GEMM: C[M,N] = A[M,K] * Bt[N,K]^T + bias ----------------
// A f32 or bf16 (converted to bf16 during LDS staging). Bt bf16. bias f32. C f32 or bf16.
#define BM 128
#define BN 128
#define BKK 32
#define LDST 40   // LDS row stride (bf16 elems)

template <typename AT, typename OT>
__global__ __launch_bounds__(256) void gemm_bt(
    const AT* __restrict__ A,                // [M,K] row-major
    const unsigned short* __restrict__ Bt,   // [N,K] bf16 row-major (B transposed)
    const float* __restrict__ bias,          // [N] f32
    OT* __restrict__ C,                      // [M,N]
    int N, int K)
{
    __shared__ __align__(16) unsigned short As[BM * LDST];
    __shared__ __align__(16) unsigned short Bs[BN * LDST];
    const int tid  = threadIdx.x;
    const int bm   = blockIdx.y, bn = blockIdx.x;
    const int w    = tid >> 6, lane = tid & 63;
    const int wm   = (w >> 1) * 64, wn = (w & 1) * 64;
    const int l16  = lane & 15, quad = lane >> 4;
    const int srow = tid >> 1, soff = (tid & 1) * 16;

    const AT* pa             = A  + (long)(bm * BM + srow) * K + soff;
    const unsigned short* pb = Bt + (long)(bn * BN + srow) * K + soff;
    unsigned short* wa = &As[srow * LDST + soff];
    unsigned short* wb = &Bs[srow * LDST + soff];

    floatx4 acc[4][4] = {};

    for (int k0 = 0; k0 < K; k0 += BKK) {
        uint4 alo, ahi, blo, bhi;
        ldconv16(pa, alo, ahi);
        ldconv16(pb, blo, bhi);
        pa += BKK; pb += BKK;
        __syncthreads();                 // prior iter's LDS reads done
        *(uint4*)(wa)     = alo; *(uint4*)(wa + 8) = ahi;
        *(uint4*)(wb)     = blo; *(uint4*)(wb + 8) = bhi;
        __syncthreads();
        short8 af[4], bf[4];
#pragma unroll
        for (int i = 0; i < 4; i++) {
            af[i] = *(const short8*)&As[(wm + i * 16 + l16) * LDST + quad * 8];
            bf[i] = *(const short8*)&Bs[(wn + i * 16 + l16) * LDST + quad * 8];
        }
#pragma unroll
        for (int i = 0; i < 4; i++)
#pragma unroll
            for (int j = 0; j < 4; j++)
                acc[i][j] = __builtin_amdgcn_mfma_f32_16x16x32_bf16(af[i], bf[j], acc[i][j], 0, 0, 0);
    }

#pragma unroll
    for (int i = 0; i < 4; i++) {
        int m0 = bm * BM + wm + i * 16 + quad * 4;
#pragma unroll
        for (int j = 0; j < 4; j++) {
            int n = bn * BN + wn + j * 16 + l16;
            float bv = bias[n];
            long base = (long)m0 * N + n;
#pragma unroll
            for (int r = 0; r < 4; r++)
                store_out(C + base + (long)r * N, acc[i][j][r] + bv);
        }
    }
}

// ---------------- context[b,h,d,e] = sum_t exp(k[t,d]) * v[t,e] (UNNORMALIZED) ----------------
// Also accumulates S[b,d] = sum_t exp(k[t,d]) so the caller can normalize later.
// Max-shift is skipped: k ~ N(0,1) (max over 4096 ~ 4), so exp/sums are far from
// f32 overflow; result is mathematically identical to softmax up to rounding.
__global__ __launch_bounds__(256) void context_kernel(
    const unsigned short* __restrict__ kvb,
    float* __restrict__ ctx,     // [B,H,64,64] f32, pre-zeroed
    float* __restrict__ Sbuf)    // [B,1024] f32, pre-zeroed
{
    int chunk = blockIdx.x;        // 0..7, each covers 512 t
    int h = blockIdx.y, b = blockIdx.z;
    __shared__ float Ks[16][64];
    __shared__ float Vs[16][64];
    __shared__ float Ssh[16][64];
    int tid = threadIdx.x;
    int srow = tid >> 4;
    int scol = (tid & 15) * 8;
    int td = tid & 15, te = tid >> 4;
    long colbase = (scol < 64) ? (long)(h * 64 + scol) : (long)(1024 + h * 64 + scol - 64);
    float acc[4][4] = {};
    float ssum[8] = {};            // per-thread partial column sums (k-staging threads only)

    for (int t0 = chunk * 512; t0 < (chunk + 1) * 512; t0 += 16) {
        uint4 raw = *(const uint4*)(kvb + (long)(b * T_SEQ + t0 + srow) * 2048 + colbase);
        unsigned short u[8];
        *(uint4*)u = raw;
        if (scol < 64) {
#pragma unroll
            for (int j = 0; j < 8; j++) {
                float e = __expf(b2f(u[j]));
                Ks[srow][scol + j] = e;
                ssum[j] += e;
            }
        } else {
#pragma unroll
            for (int j = 0; j < 8; j++)
                Vs[srow][scol - 64 + j] = b2f(u[j]);
        }
        __syncthreads();
#pragma unroll
        for (int t = 0; t < 16; t++) {
            float k4[4], v4[4];
#pragma unroll
            for (int i = 0; i < 4; i++) k4[i] = Ks[t][td * 4 + i];
#pragma unroll
            for (int j = 0; j < 4; j++) v4[j] = Vs[t][te * 4 + j];
#pragma unroll
            for (int i = 0; i < 4; i++)
#pragma unroll
                for (int j = 0; j < 4; j++) acc[i][j] = fmaf(k4[i], v4[j], acc[i][j]);
        }
        __syncthreads();
    }

    // reduce denominator partials: 16 srow-partials per column -> 1 atomic per column
    if (scol < 64) {
#pragma unroll
        for (int j = 0; j < 8; j++) Ssh[srow][scol + j] = ssum[j];
    }
    __syncthreads();
    if (tid < 64) {
        float s = 0.f;
#pragma unroll
        for (int r = 0; r < 16; r++) s += Ssh[r][tid];
        atomicAdd(&Sbuf[b * 1024 + h * 64 + tid], s);
    }

    float* cb = ctx + (long)(b * NH + h) * 4096;
#pragma unroll
    for (int i = 0; i < 4; i++)
#pragma unroll
        for (int j = 0; j < 4; j++)
            atomicAdd(&cb[(td * 4 + i) * 64 + te * 4 + j], acc[i][j]);
}

// ---------------- attn: q[t,h,:] @ (context[h]/S) -> overwrite q buffer in place ----------------
__global__ __launch_bounds__(256) void attn_apply(
    unsigned short* __restrict__ qb,        // [M,1024] bf16, overwritten with result
    const float* __restrict__ ctx,
    const float* __restrict__ Sbuf)
{
    int tc = blockIdx.x, h = blockIdx.y, b = blockIdx.z;
    __shared__ __align__(16) float Cs[64][64];   // [d][e], normalized
    __shared__ __align__(16) float Qs[64][64];   // [t][d]
    int tid = threadIdx.x;
    const float* cb = ctx + (long)(b * NH + h) * 4096;
    const float* Sb = Sbuf + b * 1024 + h * 64;
#pragma unroll
    for (int i = 0; i < 4; i++) {
        int idx = i * 256 + tid;
        float4 cv = ((const float4*)cb)[idx];
        float inv = 1.0f / Sb[idx >> 4];         // d = (idx*4)>>6
        cv.x *= inv; cv.y *= inv; cv.z *= inv; cv.w *= inv;
        ((float4*)Cs)[idx] = cv;
    }
    int srow = tid >> 2, scol = (tid & 3) * 16;
    const unsigned short* qp = qb + (long)(b * T_SEQ + tc * 64 + srow) * 1024 + h * 64 + scol;
    uint4 r0 = *(const uint4*)qp;
    uint4 r1 = *(const uint4*)(qp + 8);
    unsigned short u[16];
    *(uint4*)u = r0; *(uint4*)(u + 8) = r1;
#pragma unroll
    for (int j = 0; j < 16; j++) Qs[srow][scol + j] = b2f(u[j]);
    __syncthreads();                 // all global reads staged before in-place writes
    int e = tid & 63, tq = tid >> 6;
#pragma unroll 4
    for (int ti = 0; ti < 16; ti++) {
        int t = tq * 16 + ti;
        float acc = 0.f;
#pragma unroll
        for (int dd = 0; dd < 64; dd++) acc = fmaf(Qs[t][dd], Cs[dd][e], acc);
        qb[(long)(b * T_SEQ + tc * 64 + t) * 1024 + h * 64 + e] = f2b(acc);
    }
}

// ---------------- launch ----------------
extern "C" void kernel_launch(void* const* d_in, const int* in_sizes, int n_in,
                              void* d_out, int out_size, void* d_ws, size_t ws_size,
                              hipStream_t stream) {
    const float* x     = (const float*)d_in[0];
    const float* z     = (const float*)d_in[1];
    const float* w_q   = (const float*)d_in[2];
    const float* b_q   = (const float*)d_in[3];
    const float* w_kv  = (const float*)d_in[4];
    const float* b_kv  = (const float*)d_in[5];
    const float* w_out = (const float*)d_in[6];
    const float* b_out = (const float*)d_in[7];
    float* out = (float*)d_out;            // reference output dtype is float32

    char* ws = (char*)d_ws;
    unsigned short* kvb   = (unsigned short*)(ws);                  // [16384,2048] bf16 = 64 MB
    unsigned short* qb    = (unsigned short*)(ws + 67108864);       // [16384,1024] bf16 = 32 MB
    unsigned short* wqT   = (unsigned short*)(ws + 100663296);      // 2 MB
    unsigned short* wkvT  = (unsigned short*)(ws + 102760448);      // 4 MB
    unsigned short* woutT = (unsigned short*)(ws + 106954752);      // 2 MB
    float* Sbuf  = (float*)(ws + 109051904);                        // 16 KB
    float* ctx   = (float*)(ws + 109084672);                        // 256 KB slot (1 MB used)

    hipMemsetAsync(ctx, 0, (size_t)BATCH * NH * 64 * 64 * 4, stream);
    hipMemsetAsync(Sbuf, 0, (size_t)BATCH * 1024 * 4, stream);
    transpose_w<<<4096, 256, 0, stream>>>(w_q, w_kv, w_out, wqT, wkvT, woutT);
    // q = x @ w_q + b_q   [16384,1024] bf16
    gemm_bt<float, unsigned short><<<dim3(8, 128), 256, 0, stream>>>(x, wqT, b_q, qb, 1024, 1024);
    // kv = z @ w_kv + b_kv   [16384,2048] bf16
    gemm_bt<float, unsigned short><<<dim3(16, 128), 256, 0, stream>>>(z, wkvT, b_kv, kvb, 2048, 1024);
    // fused: unnormalized context + denominator S (softmax_stats kernel eliminated)
    context_kernel<<<dim3(8, NH, BATCH), 256, 0, stream>>>(kvb, ctx, Sbuf);
    attn_apply<<<dim3(T_SEQ / 64, NH, BATCH), 256, 0, stream>>>(qb, ctx, Sbuf);
    // out = attn @ w_out + b_out   [16384,1024] f32 -> d_out
    gemm_bt<unsigned short, float><<<dim3(8, 128), 256, 0, stream>>>(qb, woutT, b_out, out, 1024, 1024);
}

// Round 2
// 517.421 us; speedup vs baseline: 1.8074x; 1.1649x over previous
//
#include <hip/hip_runtime.h>

// ---------------- problem constants ----------------
#define T_SEQ 4096
#define BATCH 4
#define NH 16
#define M_ROWS 16384

typedef __attribute__((ext_vector_type(8))) short short8;
typedef __attribute__((ext_vector_type(4))) float floatx4;

__device__ __forceinline__ float b2f(unsigned short u) {
    union { unsigned int i; float f; } x; x.i = ((unsigned int)u) << 16; return x.f;
}
__device__ __forceinline__ unsigned short f2b(float f) {
    union { float f; unsigned int i; } x; x.f = f;
    unsigned int u = x.i;
    u += 0x7fffu + ((u >> 16) & 1u);   // RNE
    return (unsigned short)(u >> 16);
}

__device__ __forceinline__ void store_out(float* p, float v) { *p = v; }
__device__ __forceinline__ void store_out(unsigned short* p, float v) { *p = f2b(v); }

// async global->LDS, 16B per lane; LDS dest must be wave-uniform base (lane*16 implicit)
__device__ __forceinline__ void gload_lds16(const unsigned short* g, unsigned short* l) {
    __builtin_amdgcn_global_load_lds(
        (const __attribute__((address_space(1))) void*)g,
        (__attribute__((address_space(3))) void*)l, 16, 0, 0);
}

// ---------------- f32 -> bf16 bulk convert: x,z -> xb,zb ----------------
__global__ __launch_bounds__(256) void convert_bf16(
    const float* __restrict__ x, const float* __restrict__ z,
    unsigned short* __restrict__ xb, unsigned short* __restrict__ zb)
{
    const float* s      = blockIdx.y ? z : x;
    unsigned short* d   = blockIdx.y ? zb : xb;
    long i = ((long)blockIdx.x * 256 + threadIdx.x) * 8;
    float4 f0 = *(const float4*)(s + i);
    float4 f1 = *(const float4*)(s + i + 4);
    unsigned short u[8];
    u[0] = f2b(f0.x); u[1] = f2b(f0.y); u[2] = f2b(f0.z); u[3] = f2b(f0.w);
    u[4] = f2b(f1.x); u[5] = f2b(f1.y); u[6] = f2b(f1.z); u[7] = f2b(f1.w);
    *(uint4*)(d + i) = *(uint4*)u;
}

// ---------------- weight transpose+convert: W[K][N] f32 -> Wt[N][K] bf16 ----------------
__global__ __launch_bounds__(256) void transpose_w(
    const float* __restrict__ wq,
    const float* __restrict__ wkv,
    const float* __restrict__ wout,
    unsigned short* __restrict__ wqT,
    unsigned short* __restrict__ wkvT,
    unsigned short* __restrict__ woutT)
{
    int bid = blockIdx.x;
    const float* src; unsigned short* dst; int Nd; int local;
    if (bid < 1024)      { src = wq;   dst = wqT;   Nd = 1024; local = bid; }
    else if (bid < 3072) { src = wkv;  dst = wkvT;  Nd = 2048; local = bid - 1024; }
    else                 { src = wout; dst = woutT; Nd = 1024; local = bid - 3072; }
    int tilesN = Nd >> 5;
    int tk = local / tilesN, tn = local % tilesN;
    __shared__ __align__(16) unsigned short tile[32][36];
    int tid = threadIdx.x;
    int r = tid >> 3, c = (tid & 7) * 4;
    float4 in = *(const float4*)(src + (long)(tk * 32 + r) * Nd + tn * 32 + c);
    tile[r][c] = f2b(in.x); tile[r][c + 1] = f2b(in.y);
    tile[r][c + 2] = f2b(in.z); tile[r][c + 3] = f2b(in.w);
    __syncthreads();
    ushort4 o;
    o.x = tile[c][r]; o.y = tile[c + 1][r]; o.z = tile[c + 2][r]; o.w = tile[c + 3][r];
    *(ushort4*)(dst + (long)(tn * 32 + r) * 1024 + tk * 32 + c) = o;
}

// ---------------- bf16 MFMA GEMM (m97 structure): C[M,N] = A[M,K]*Bt[N,K]^T + bias ----------------
// A bf16, Bt bf16, bias f32, C f32 or bf16. Linear LDS tiles + global_load_lds w=16.
#define BM 128
#define BN 128
#define BKK 32

template <typename OT>
__global__ __launch_bounds__(256) void gemm_bt(
    const unsigned short* __restrict__ A,    // [M,K] bf16 row-major
    const unsigned short* __restrict__ Bt,   // [N,K] bf16 row-major (B transposed)
    const float* __restrict__ bias,          // [N] f32
    OT* __restrict__ C,                      // [M,N]
    int N, int K)
{
    __shared__ __align__(16) unsigned short As[BM * BKK];
    __shared__ __align__(16) unsigned short Bs[BN * BKK];
    const int tid  = threadIdx.x;

    // bijective XCD-aware swizzle (nwg % 8 == 0 for all our launches)
    const int gx   = gridDim.x;
    const int nwg  = gx * gridDim.y;
    const int flat = blockIdx.y * gx + blockIdx.x;
    const int swz  = (flat & 7) * (nwg >> 3) + (flat >> 3);
    const int bn   = swz % gx, bm = swz / gx;

    const int w    = tid >> 6, lane = tid & 63;
    const int wm   = (w >> 1) * 64, wn = (w & 1) * 64;
    const int l16  = lane & 15, quad = lane >> 4;

    // staging: wave w owns rows 32w..32w+31 of both tiles; 2x 1KB loads per operand
    const int r0 = w * 32 + (lane >> 2);
    const int c0 = (lane & 3) * 8;
    const unsigned short* pa0 = A  + (long)(bm * BM + r0) * K + c0;
    const unsigned short* pa1 = pa0 + (long)16 * K;
    const unsigned short* pb0 = Bt + (long)(bn * BN + r0) * K + c0;
    const unsigned short* pb1 = pb0 + (long)16 * K;
    unsigned short* la0 = &As[(w * 32) * BKK];       // wave-uniform LDS bases
    unsigned short* la1 = &As[(w * 32 + 16) * BKK];
    unsigned short* lb0 = &Bs[(w * 32) * BKK];
    unsigned short* lb1 = &Bs[(w * 32 + 16) * BKK];

    floatx4 acc[4][4] = {};

    for (int k0 = 0; k0 < K; k0 += BKK) {
        __syncthreads();                  // prior iter's ds_reads done before overwrite
        gload_lds16(pa0 + k0, la0);
        gload_lds16(pa1 + k0, la1);
        gload_lds16(pb0 + k0, lb0);
        gload_lds16(pb1 + k0, lb1);
        __syncthreads();                  // drains vmcnt (loads landed in LDS)
        short8 af[4], bf[4];
#pragma unroll
        for (int i = 0; i < 4; i++) {
            af[i] = *(const short8*)&As[(wm + i * 16 + l16) * BKK + quad * 8];
            bf[i] = *(const short8*)&Bs[(wn + i * 16 + l16) * BKK + quad * 8];
        }
#pragma unroll
        for (int i = 0; i < 4; i++)
#pragma unroll
            for (int j = 0; j < 4; j++)
                acc[i][j] = __builtin_amdgcn_mfma_f32_16x16x32_bf16(af[i], bf[j], acc[i][j], 0, 0, 0);
    }

#pragma unroll
    for (int i = 0; i < 4; i++) {
        int m0 = bm * BM + wm + i * 16 + quad * 4;
#pragma unroll
        for (int j = 0; j < 4; j++) {
            int n = bn * BN + wn + j * 16 + l16;
            float bv = bias[n];
            long base = (long)m0 * N + n;
#pragma unroll
            for (int r = 0; r < 4; r++)
                store_out(C + base + (long)r * N, acc[i][j][r] + bv);
        }
    }
}

// ---------------- context[b,h,d,e] = sum_t exp(k[t,d]) * v[t,e] (UNNORMALIZED) ----------------
// Also accumulates S[b,d] = sum_t exp(k[t,d]). Max-shift skipped: k ~ N(0,1), far from
// f32 overflow; identical to softmax up to rounding.
__global__ __launch_bounds__(256) void context_kernel(
    const unsigned short* __restrict__ kvb,
    float* __restrict__ ctx,     // [B,H,64,64] f32, pre-zeroed
    float* __restrict__ Sbuf)    // [B,1024] f32, pre-zeroed
{
    int chunk = blockIdx.x;        // 0..7, each covers 512 t
    int h = blockIdx.y, b = blockIdx.z;
    __shared__ float Ks[16][64];
    __shared__ float Vs[16][64];
    __shared__ float Ssh[16][64];
    int tid = threadIdx.x;
    int srow = tid >> 4;
    int scol = (tid & 15) * 8;
    int td = tid & 15, te = tid >> 4;
    long colbase = (scol < 64) ? (long)(h * 64 + scol) : (long)(1024 + h * 64 + scol - 64);
    float acc[4][4] = {};
    float ssum[8] = {};

    for (int t0 = chunk * 512; t0 < (chunk + 1) * 512; t0 += 16) {
        uint4 raw = *(const uint4*)(kvb + (long)(b * T_SEQ + t0 + srow) * 2048 + colbase);
        unsigned short u[8];
        *(uint4*)u = raw;
        if (scol < 64) {
#pragma unroll
            for (int j = 0; j < 8; j++) {
                float e = __expf(b2f(u[j]));
                Ks[srow][scol + j] = e;
                ssum[j] += e;
            }
        } else {
#pragma unroll
            for (int j = 0; j < 8; j++)
                Vs[srow][scol - 64 + j] = b2f(u[j]);
        }
        __syncthreads();
#pragma unroll
        for (int t = 0; t < 16; t++) {
            float k4[4], v4[4];
#pragma unroll
            for (int i = 0; i < 4; i++) k4[i] = Ks[t][td * 4 + i];
#pragma unroll
            for (int j = 0; j < 4; j++) v4[j] = Vs[t][te * 4 + j];
#pragma unroll
            for (int i = 0; i < 4; i++)
#pragma unroll
                for (int j = 0; j < 4; j++) acc[i][j] = fmaf(k4[i], v4[j], acc[i][j]);
        }
        __syncthreads();
    }

    if (scol < 64) {
#pragma unroll
        for (int j = 0; j < 8; j++) Ssh[srow][scol + j] = ssum[j];
    }
    __syncthreads();
    if (tid < 64) {
        float s = 0.f;
#pragma unroll
        for (int r = 0; r < 16; r++) s += Ssh[r][tid];
        atomicAdd(&Sbuf[b * 1024 + h * 64 + tid], s);
    }

    float* cb = ctx + (long)(b * NH + h) * 4096;
#pragma unroll
    for (int i = 0; i < 4; i++)
#pragma unroll
        for (int j = 0; j < 4; j++)
            atomicAdd(&cb[(td * 4 + i) * 64 + te * 4 + j], acc[i][j]);
}

// ---------------- attn: q[t,h,:] @ (context[h]/S) -> overwrite q buffer in place ----------------
__global__ __launch_bounds__(256) void attn_apply(
    unsigned short* __restrict__ qb,        // [M,1024] bf16, overwritten with result
    const float* __restrict__ ctx,
    const float* __restrict__ Sbuf)
{
    int tc = blockIdx.x, h = blockIdx.y, b = blockIdx.z;
    __shared__ __align__(16) float Cs[64][64];   // [d][e], normalized
    __shared__ __align__(16) float Qs[64][64];   // [t][d]
    int tid = threadIdx.x;
    const float* cb = ctx + (long)(b * NH + h) * 4096;
    const float* Sb = Sbuf + b * 1024 + h * 64;
#pragma unroll
    for (int i = 0; i < 4; i++) {
        int idx = i * 256 + tid;
        float4 cv = ((const float4*)cb)[idx];
        float inv = 1.0f / Sb[idx >> 4];
        cv.x *= inv; cv.y *= inv; cv.z *= inv; cv.w *= inv;
        ((float4*)Cs)[idx] = cv;
    }
    int srow = tid >> 2, scol = (tid & 3) * 16;
    const unsigned short* qp = qb + (long)(b * T_SEQ + tc * 64 + srow) * 1024 + h * 64 + scol;
    uint4 r0 = *(const uint4*)qp;
    uint4 r1 = *(const uint4*)(qp + 8);
    unsigned short u[16];
    *(uint4*)u = r0; *(uint4*)(u + 8) = r1;
#pragma unroll
    for (int j = 0; j < 16; j++) Qs[srow][scol + j] = b2f(u[j]);
    __syncthreads();                 // all global reads staged before in-place writes
    int e = tid & 63, tq = tid >> 6;
#pragma unroll 4
    for (int ti = 0; ti < 16; ti++) {
        int t = tq * 16 + ti;
        float acc = 0.f;
#pragma unroll
        for (int dd = 0; dd < 64; dd++) acc = fmaf(Qs[t][dd], Cs[dd][e], acc);
        qb[(long)(b * T_SEQ + tc * 64 + t) * 1024 + h * 64 + e] = f2b(acc);
    }
}

// ---------------- launch ----------------
extern "C" void kernel_launch(void* const* d_in, const int* in_sizes, int n_in,
                              void* d_out, int out_size, void* d_ws, size_t ws_size,
                              hipStream_t stream) {
    const float* x     = (const float*)d_in[0];
    const float* z     = (const float*)d_in[1];
    const float* w_q   = (const float*)d_in[2];
    const float* b_q   = (const float*)d_in[3];
    const float* w_kv  = (const float*)d_in[4];
    const float* b_kv  = (const float*)d_in[5];
    const float* w_out = (const float*)d_in[6];
    const float* b_out = (const float*)d_in[7];
    float* out = (float*)d_out;            // reference output dtype is float32

    char* ws = (char*)d_ws;
    unsigned short* kvb   = (unsigned short*)(ws);                  // [16384,2048] bf16 = 64 MB
    unsigned short* qb    = (unsigned short*)(ws + 67108864);       // [16384,1024] bf16 = 32 MB
    unsigned short* wqT   = (unsigned short*)(ws + 100663296);      // 2 MB
    unsigned short* wkvT  = (unsigned short*)(ws + 102760448);      // 4 MB
    unsigned short* woutT = (unsigned short*)(ws + 106954752);      // 2 MB
    float* Sbuf  = (float*)(ws + 109051904);                        // 16 KB
    float* ctx   = (float*)(ws + 109084672);                        // 256 KB slot (1 MB used)

    // xb/zb (bf16 copies of x,z) live inside d_out: dead once q/kv GEMMs complete,
    // and d_out is only written by the final GEMM. 32 MB + 32 MB = exactly out_size.
    unsigned short* xb = (unsigned short*)d_out;
    unsigned short* zb = (unsigned short*)((char*)d_out + 33554432);

    hipMemsetAsync(ctx, 0, (size_t)BATCH * NH * 64 * 64 * 4, stream);
    hipMemsetAsync(Sbuf, 0, (size_t)BATCH * 1024 * 4, stream);
    convert_bf16<<<dim3(8192, 2), 256, 0, stream>>>(x, z, xb, zb);
    transpose_w<<<4096, 256, 0, stream>>>(w_q, w_kv, w_out, wqT, wkvT, woutT);
    // q = x @ w_q + b_q   [16384,1024] bf16
    gemm_bt<unsigned short><<<dim3(8, 128), 256, 0, stream>>>(xb, wqT, b_q, qb, 1024, 1024);
    // kv = z @ w_kv + b_kv   [16384,2048] bf16
    gemm_bt<unsigned short><<<dim3(16, 128), 256, 0, stream>>>(zb, wkvT, b_kv, kvb, 2048, 1024);
    // fused: unnormalized context + denominator S
    context_kernel<<<dim3(8, NH, BATCH), 256, 0, stream>>>(kvb, ctx, Sbuf);
    attn_apply<<<dim3(T_SEQ / 64, NH, BATCH), 256, 0, stream>>>(qb, ctx, Sbuf);
    // out = attn @ w_out + b_out   [16384,1024] f32 -> d_out
    gemm_bt<float><<<dim3(8, 128), 256, 0, stream>>>(qb, woutT, b_out, out, 1024, 1024);
}

// Round 3
// 472.809 us; speedup vs baseline: 1.9780x; 1.0944x over previous
//
#include <hip/hip_runtime.h>

// ---------------- problem constants ----------------
#define T_SEQ 4096
#define BATCH 4
#define NH 16
#define M_ROWS 16384

typedef __attribute__((ext_vector_type(8))) short short8;
typedef __attribute__((ext_vector_type(4))) float floatx4;

__device__ __forceinline__ float b2f(unsigned short u) {
    union { unsigned int i; float f; } x; x.i = ((unsigned int)u) << 16; return x.f;
}
__device__ __forceinline__ unsigned short f2b(float f) {
    union { float f; unsigned int i; } x; x.f = f;
    unsigned int u = x.i;
    u += 0x7fffu + ((u >> 16) & 1u);   // RNE
    return (unsigned short)(u >> 16);
}

__device__ __forceinline__ void store_out(float* p, float v) { *p = v; }
__device__ __forceinline__ void store_out(unsigned short* p, float v) { *p = f2b(v); }

// async global->LDS, 16B per lane; LDS dest must be wave-uniform base (lane*16 implicit)
__device__ __forceinline__ void gload_lds16(const unsigned short* g, unsigned short* l) {
    __builtin_amdgcn_global_load_lds(
        (const __attribute__((address_space(1))) void*)g,
        (__attribute__((address_space(3))) void*)l, 16, 0, 0);
}

// ---------------- f32 -> bf16 bulk convert: x,z -> xb,zb ----------------
__global__ __launch_bounds__(256) void convert_bf16(
    const float* __restrict__ x, const float* __restrict__ z,
    unsigned short* __restrict__ xb, unsigned short* __restrict__ zb)
{
    const float* s      = blockIdx.y ? z : x;
    unsigned short* d   = blockIdx.y ? zb : xb;
    long i = ((long)blockIdx.x * 256 + threadIdx.x) * 8;
    float4 f0 = *(const float4*)(s + i);
    float4 f1 = *(const float4*)(s + i + 4);
    unsigned short u[8];
    u[0] = f2b(f0.x); u[1] = f2b(f0.y); u[2] = f2b(f0.z); u[3] = f2b(f0.w);
    u[4] = f2b(f1.x); u[5] = f2b(f1.y); u[6] = f2b(f1.z); u[7] = f2b(f1.w);
    *(uint4*)(d + i) = *(uint4*)u;
}

// ---------------- weight transpose+convert: W[K][N] f32 -> Wt[N][K] bf16 ----------------
__global__ __launch_bounds__(256) void transpose_w(
    const float* __restrict__ wq,
    const float* __restrict__ wkv,
    const float* __restrict__ wout,
    unsigned short* __restrict__ wqT,
    unsigned short* __restrict__ wkvT,
    unsigned short* __restrict__ woutT)
{
    int bid = blockIdx.x;
    const float* src; unsigned short* dst; int Nd; int local;
    if (bid < 1024)      { src = wq;   dst = wqT;   Nd = 1024; local = bid; }
    else if (bid < 3072) { src = wkv;  dst = wkvT;  Nd = 2048; local = bid - 1024; }
    else                 { src = wout; dst = woutT; Nd = 1024; local = bid - 3072; }
    int tilesN = Nd >> 5;
    int tk = local / tilesN, tn = local % tilesN;
    __shared__ __align__(16) unsigned short tile[32][36];
    int tid = threadIdx.x;
    int r = tid >> 3, c = (tid & 7) * 4;
    float4 in = *(const float4*)(src + (long)(tk * 32 + r) * Nd + tn * 32 + c);
    tile[r][c] = f2b(in.x); tile[r][c + 1] = f2b(in.y);
    tile[r][c + 2] = f2b(in.z); tile[r][c + 3] = f2b(in.w);
    __syncthreads();
    ushort4 o;
    o.x = tile[c][r]; o.y = tile[c + 1][r]; o.z = tile[c + 2][r]; o.w = tile[c + 3][r];
    *(ushort4*)(dst + (long)(tn * 32 + r) * 1024 + tk * 32 + c) = o;
}

// ---------------- bf16 MFMA GEMM (m97 structure): C[M,N] = A[M,K]*Bt[N,K]^T + bias ----------------
#define BM 128
#define BN 128
#define BKK 32

template <typename OT>
__global__ __launch_bounds__(256) void gemm_bt(
    const unsigned short* __restrict__ A,    // [M,K] bf16 row-major
    const unsigned short* __restrict__ Bt,   // [N,K] bf16 row-major (B transposed)
    const float* __restrict__ bias,          // [N] f32
    OT* __restrict__ C,                      // [M,N]
    int N, int K)
{
    __shared__ __align__(16) unsigned short As[BM * BKK];
    __shared__ __align__(16) unsigned short Bs[BN * BKK];
    const int tid  = threadIdx.x;

    // bijective XCD-aware swizzle (nwg % 8 == 0 for all our launches)
    const int gx   = gridDim.x;
    const int nwg  = gx * gridDim.y;
    const int flat = blockIdx.y * gx + blockIdx.x;
    const int swz  = (flat & 7) * (nwg >> 3) + (flat >> 3);
    const int bn   = swz % gx, bm = swz / gx;

    const int w    = tid >> 6, lane = tid & 63;
    const int wm   = (w >> 1) * 64, wn = (w & 1) * 64;
    const int l16  = lane & 15, quad = lane >> 4;

    const int r0 = w * 32 + (lane >> 2);
    const int c0 = (lane & 3) * 8;
    const unsigned short* pa0 = A  + (long)(bm * BM + r0) * K + c0;
    const unsigned short* pa1 = pa0 + (long)16 * K;
    const unsigned short* pb0 = Bt + (long)(bn * BN + r0) * K + c0;
    const unsigned short* pb1 = pb0 + (long)16 * K;
    unsigned short* la0 = &As[(w * 32) * BKK];
    unsigned short* la1 = &As[(w * 32 + 16) * BKK];
    unsigned short* lb0 = &Bs[(w * 32) * BKK];
    unsigned short* lb1 = &Bs[(w * 32 + 16) * BKK];

    floatx4 acc[4][4] = {};

    for (int k0 = 0; k0 < K; k0 += BKK) {
        __syncthreads();
        gload_lds16(pa0 + k0, la0);
        gload_lds16(pa1 + k0, la1);
        gload_lds16(pb0 + k0, lb0);
        gload_lds16(pb1 + k0, lb1);
        __syncthreads();
        short8 af[4], bf[4];
#pragma unroll
        for (int i = 0; i < 4; i++) {
            af[i] = *(const short8*)&As[(wm + i * 16 + l16) * BKK + quad * 8];
            bf[i] = *(const short8*)&Bs[(wn + i * 16 + l16) * BKK + quad * 8];
        }
#pragma unroll
        for (int i = 0; i < 4; i++)
#pragma unroll
            for (int j = 0; j < 4; j++)
                acc[i][j] = __builtin_amdgcn_mfma_f32_16x16x32_bf16(af[i], bf[j], acc[i][j], 0, 0, 0);
    }

#pragma unroll
    for (int i = 0; i < 4; i++) {
        int m0 = bm * BM + wm + i * 16 + quad * 4;
#pragma unroll
        for (int j = 0; j < 4; j++) {
            int n = bn * BN + wn + j * 16 + l16;
            float bv = bias[n];
            long base = (long)m0 * N + n;
#pragma unroll
            for (int r = 0; r < 4; r++)
                store_out(C + base + (long)r * N, acc[i][j][r] + bv);
        }
    }
}

// ---------------- context[b,h,d,e] = sum_t exp(k[t,d]) * v[t,e] (UNNORMALIZED) ----------------
// Also accumulates S[b,d] = sum_t exp(k[t,d]). Max-shift skipped: k ~ N(0,1), far from
// f32 overflow; identical to softmax up to rounding.
__global__ __launch_bounds__(256) void context_kernel(
    const unsigned short* __restrict__ kvb,
    float* __restrict__ ctx,     // [B,H,64,64] f32, pre-zeroed
    float* __restrict__ Sbuf)    // [B,1024] f32, pre-zeroed
{
    int chunk = blockIdx.x;        // 0..7, each covers 512 t
    int h = blockIdx.y, b = blockIdx.z;
    __shared__ float Ks[16][64];
    __shared__ float Vs[16][64];
    __shared__ float Ssh[16][64];
    int tid = threadIdx.x;
    int srow = tid >> 4;
    int scol = (tid & 15) * 8;
    int td = tid & 15, te = tid >> 4;
    long colbase = (scol < 64) ? (long)(h * 64 + scol) : (long)(1024 + h * 64 + scol - 64);
    float acc[4][4] = {};
    float ssum[8] = {};

    for (int t0 = chunk * 512; t0 < (chunk + 1) * 512; t0 += 16) {
        uint4 raw = *(const uint4*)(kvb + (long)(b * T_SEQ + t0 + srow) * 2048 + colbase);
        unsigned short u[8];
        *(uint4*)u = raw;
        if (scol < 64) {
#pragma unroll
            for (int j = 0; j < 8; j++) {
                float e = __expf(b2f(u[j]));
                Ks[srow][scol + j] = e;
                ssum[j] += e;
            }
        } else {
#pragma unroll
            for (int j = 0; j < 8; j++)
                Vs[srow][scol - 64 + j] = b2f(u[j]);
        }
        __syncthreads();
#pragma unroll
        for (int t = 0; t < 16; t++) {
            float k4[4], v4[4];
#pragma unroll
            for (int i = 0; i < 4; i++) k4[i] = Ks[t][td * 4 + i];
#pragma unroll
            for (int j = 0; j < 4; j++) v4[j] = Vs[t][te * 4 + j];
#pragma unroll
            for (int i = 0; i < 4; i++)
#pragma unroll
                for (int j = 0; j < 4; j++) acc[i][j] = fmaf(k4[i], v4[j], acc[i][j]);
        }
        __syncthreads();
    }

    if (scol < 64) {
#pragma unroll
        for (int j = 0; j < 8; j++) Ssh[srow][scol + j] = ssum[j];
    }
    __syncthreads();
    if (tid < 64) {
        float s = 0.f;
#pragma unroll
        for (int r = 0; r < 16; r++) s += Ssh[r][tid];
        atomicAdd(&Sbuf[b * 1024 + h * 64 + tid], s);
    }

    float* cb = ctx + (long)(b * NH + h) * 4096;
#pragma unroll
    for (int i = 0; i < 4; i++)
#pragma unroll
        for (int j = 0; j < 4; j++)
            atomicAdd(&cb[(td * 4 + i) * 64 + te * 4 + j], acc[i][j]);
}

// ---------------- finalize: ctxb[b,h,e,d] = bf16( ctx[b,h,d,e] / S[b,h*64+d] ) ----------------
// Transposed + normalized so it is directly the Bt[N=e,K=d] operand for attn MFMA.
__global__ __launch_bounds__(256) void finalize_ctx(
    const float* __restrict__ ctx, const float* __restrict__ Sbuf,
    unsigned short* __restrict__ ctxb)
{
    int bh = blockIdx.x;           // 0..63  (b*16+h)
    int b = bh >> 4, h = bh & 15;
    const float* cb = ctx + (long)bh * 4096;
    const float* Sb = Sbuf + b * 1024 + h * 64;
    unsigned short* ob = ctxb + (long)bh * 4096;
    int tid = threadIdx.x;
    int e = tid >> 2, d0 = (tid & 3) * 16;
    unsigned short u[16];
#pragma unroll
    for (int j = 0; j < 16; j++) {
        int d = d0 + j;
        u[j] = f2b(cb[d * 64 + e] * (1.0f / Sb[d]));
    }
    *(uint4*)(ob + e * 64 + d0)     = *(uint4*)u;
    *(uint4*)(ob + e * 64 + d0 + 8) = *((uint4*)u + 1);
}

// ---------------- attn via MFMA: qb[t, h*64+e] = sum_d qb[t,h*64+d] * ctxb[b,h,e,d] ----------------
// Per block: 256 t-rows of one (b,h). 4 waves x 64 rows each. B (ctx) held in VGPRs,
// A fragments read directly from global (64B-coalesced per quad group). No LDS.
// In-place safe: each wave reads/writes only its own 64 rows; stores depend on all MFMAs.
__global__ __launch_bounds__(256) void attn_mfma(
    unsigned short* __restrict__ qb,            // [16384,1024] bf16, in/out
    const unsigned short* __restrict__ ctxb)    // [B,H,64(e),64(d)] bf16 normalized
{
    int tc = blockIdx.x, h = blockIdx.y, b = blockIdx.z;
    int w = threadIdx.x >> 6, lane = threadIdx.x & 63;
    int l16 = lane & 15, quad = lane >> 4;

    const unsigned short* cb = ctxb + (long)(b * NH + h) * 4096;
    short8 bf[4][2];
#pragma unroll
    for (int j = 0; j < 4; j++)
#pragma unroll
        for (int ks = 0; ks < 2; ks++)
            bf[j][ks] = *(const short8*)(cb + (j * 16 + l16) * 64 + ks * 32 + quad * 8);

    long trow0 = (long)b * T_SEQ + tc * 256 + w * 64;
    unsigned short* qrow = qb + trow0 * 1024 + h * 64;

    short8 af[4][2];
#pragma unroll
    for (int i = 0; i < 4; i++)
#pragma unroll
        for (int ks = 0; ks < 2; ks++)
            af[i][ks] = *(const short8*)(qrow + (long)(i * 16 + l16) * 1024 + ks * 32 + quad * 8);

    floatx4 acc[4][4] = {};
#pragma unroll
    for (int i = 0; i < 4; i++)
#pragma unroll
        for (int j = 0; j < 4; j++) {
            acc[i][j] = __builtin_amdgcn_mfma_f32_16x16x32_bf16(af[i][0], bf[j][0], acc[i][j], 0, 0, 0);
            acc[i][j] = __builtin_amdgcn_mfma_f32_16x16x32_bf16(af[i][1], bf[j][1], acc[i][j], 0, 0, 0);
        }

#pragma unroll
    for (int i = 0; i < 4; i++)
#pragma unroll
        for (int j = 0; j < 4; j++)
#pragma unroll
            for (int r = 0; r < 4; r++)
                qrow[(long)(i * 16 + quad * 4 + r) * 1024 + j * 16 + l16] = f2b(acc[i][j][r]);
}

// ---------------- launch ----------------
extern "C" void kernel_launch(void* const* d_in, const int* in_sizes, int n_in,
                              void* d_out, int out_size, void* d_ws, size_t ws_size,
                              hipStream_t stream) {
    const float* x     = (const float*)d_in[0];
    const float* z     = (const float*)d_in[1];
    const float* w_q   = (const float*)d_in[2];
    const float* b_q   = (const float*)d_in[3];
    const float* w_kv  = (const float*)d_in[4];
    const float* b_kv  = (const float*)d_in[5];
    const float* w_out = (const float*)d_in[6];
    const float* b_out = (const float*)d_in[7];
    float* out = (float*)d_out;            // reference output dtype is float32

    char* ws = (char*)d_ws;
    unsigned short* kvb   = (unsigned short*)(ws);                  // [16384,2048] bf16 = 64 MB
    unsigned short* qb    = (unsigned short*)(ws + 67108864);       // [16384,1024] bf16 = 32 MB
    unsigned short* wqT   = (unsigned short*)(ws + 100663296);      // 2 MB
    unsigned short* wkvT  = (unsigned short*)(ws + 102760448);      // 4 MB
    unsigned short* woutT = (unsigned short*)(ws + 106954752);      // 2 MB
    float* Sbuf  = (float*)(ws + 109051904);                        // 16 KB
    float* ctx   = (float*)(ws + 109084672);                        // 1 MB
    unsigned short* ctxb = (unsigned short*)(ws + 110133248);       // 512 KB  (peak ~105.5 MiB)

    // xb/zb (bf16 copies of x,z) live inside d_out: dead once q/kv GEMMs complete,
    // and d_out is only written by the final GEMM.
    unsigned short* xb = (unsigned short*)d_out;
    unsigned short* zb = (unsigned short*)((char*)d_out + 33554432);

    hipMemsetAsync(ctx, 0, (size_t)BATCH * NH * 64 * 64 * 4, stream);
    hipMemsetAsync(Sbuf, 0, (size_t)BATCH * 1024 * 4, stream);
    convert_bf16<<<dim3(8192, 2), 256, 0, stream>>>(x, z, xb, zb);
    transpose_w<<<4096, 256, 0, stream>>>(w_q, w_kv, w_out, wqT, wkvT, woutT);
    // q = x @ w_q + b_q   [16384,1024] bf16
    gemm_bt<unsigned short><<<dim3(8, 128), 256, 0, stream>>>(xb, wqT, b_q, qb, 1024, 1024);
    // kv = z @ w_kv + b_kv   [16384,2048] bf16
    gemm_bt<unsigned short><<<dim3(16, 128), 256, 0, stream>>>(zb, wkvT, b_kv, kvb, 2048, 1024);
    // fused: unnormalized context + denominator S
    context_kernel<<<dim3(8, NH, BATCH), 256, 0, stream>>>(kvb, ctx, Sbuf);
    // normalize + transpose ctx to bf16 Bt layout
    finalize_ctx<<<64, 256, 0, stream>>>(ctx, Sbuf, ctxb);
    // attn: q <- q @ ctx^T (per head), in place, MFMA
    attn_mfma<<<dim3(T_SEQ / 256, NH, BATCH), 256, 0, stream>>>(qb, ctxb);
    // out = attn @ w_out + b_out   [16384,1024] f32 -> d_out
    gemm_bt<float><<<dim3(8, 128), 256, 0, stream>>>(qb, woutT, b_out, out, 1024, 1024);
}

// Round 4
// 427.291 us; speedup vs baseline: 2.1887x; 1.1065x over previous
//
#include <hip/hip_runtime.h>

// ---------------- problem constants ----------------
#define T_SEQ 4096
#define BATCH 4
#define NH 16
#define M_ROWS 16384

typedef __attribute__((ext_vector_type(8))) short short8;
typedef __attribute__((ext_vector_type(4))) float floatx4;

__device__ __forceinline__ float b2f(unsigned short u) {
    union { unsigned int i; float f; } x; x.i = ((unsigned int)u) << 16; return x.f;
}
__device__ __forceinline__ unsigned short f2b(float f) {
    union { float f; unsigned int i; } x; x.f = f;
    unsigned int u = x.i;
    u += 0x7fffu + ((u >> 16) & 1u);   // RNE
    return (unsigned short)(u >> 16);
}

__device__ __forceinline__ void store_out(float* p, float v) { *p = v; }
__device__ __forceinline__ void store_out(unsigned short* p, float v) { *p = f2b(v); }

// async global->LDS, 16B per lane; LDS dest is wave-uniform base (+lane*16 implicit)
__device__ __forceinline__ void gload_lds16(const unsigned short* g, unsigned short* l) {
    __builtin_amdgcn_global_load_lds(
        (const __attribute__((address_space(1))) void*)g,
        (__attribute__((address_space(3))) void*)l, 16, 0, 0);
}

// ---------------- f32 -> bf16 bulk convert: x,z -> xb,zb ----------------
__global__ __launch_bounds__(256) void convert_bf16(
    const float* __restrict__ x, const float* __restrict__ z,
    unsigned short* __restrict__ xb, unsigned short* __restrict__ zb)
{
    const float* s      = blockIdx.y ? z : x;
    unsigned short* d   = blockIdx.y ? zb : xb;
    long i = ((long)blockIdx.x * 256 + threadIdx.x) * 8;
    float4 f0 = *(const float4*)(s + i);
    float4 f1 = *(const float4*)(s + i + 4);
    unsigned short u[8];
    u[0] = f2b(f0.x); u[1] = f2b(f0.y); u[2] = f2b(f0.z); u[3] = f2b(f0.w);
    u[4] = f2b(f1.x); u[5] = f2b(f1.y); u[6] = f2b(f1.z); u[7] = f2b(f1.w);
    *(uint4*)(d + i) = *(uint4*)u;
}

// ---------------- weight transpose+convert: W[K][N] f32 -> Wt[N][K] bf16 ----------------
__global__ __launch_bounds__(256) void transpose_w(
    const float* __restrict__ wq,
    const float* __restrict__ wkv,
    const float* __restrict__ wout,
    unsigned short* __restrict__ wqT,
    unsigned short* __restrict__ wkvT,
    unsigned short* __restrict__ woutT)
{
    int bid = blockIdx.x;
    const float* src; unsigned short* dst; int Nd; int local;
    if (bid < 1024)      { src = wq;   dst = wqT;   Nd = 1024; local = bid; }
    else if (bid < 3072) { src = wkv;  dst = wkvT;  Nd = 2048; local = bid - 1024; }
    else                 { src = wout; dst = woutT; Nd = 1024; local = bid - 3072; }
    int tilesN = Nd >> 5;
    int tk = local / tilesN, tn = local % tilesN;
    __shared__ __align__(16) unsigned short tile[32][36];
    int tid = threadIdx.x;
    int r = tid >> 3, c = (tid & 7) * 4;
    float4 in = *(const float4*)(src + (long)(tk * 32 + r) * Nd + tn * 32 + c);
    tile[r][c] = f2b(in.x); tile[r][c + 1] = f2b(in.y);
    tile[r][c + 2] = f2b(in.z); tile[r][c + 3] = f2b(in.w);
    __syncthreads();
    ushort4 o;
    o.x = tile[c][r]; o.y = tile[c + 1][r]; o.z = tile[c + 2][r]; o.w = tile[c + 3][r];
    *(ushort4*)(dst + (long)(tn * 32 + r) * 1024 + tk * 32 + c) = o;
}

// ---------------- deep-pipelined bf16 MFMA GEMM: C[M,N] = A[M,K]*Bt[N,K]^T + bias ----------
// 256x256 tile, BK=32, 8 waves (2M x 4N), 4-deep LDS ring (128 KiB), counted vmcnt
// (never 0 in steady state), setprio around MFMA cluster, XOR bank swizzle applied as
// inverse-permuted global source (gload_lds writes linearly) + swizzled ds_read.
#define WGS 512

template <int K, typename OT>
__global__ __launch_bounds__(WGS, 2) void gemm_bt(
    const unsigned short* __restrict__ A,    // [M,K] bf16 row-major
    const unsigned short* __restrict__ Bt,   // [N,K] bf16 row-major (B transposed)
    const float* __restrict__ bias,          // [N] f32
    OT* __restrict__ C,                      // [M,N]
    int N)
{
    constexpr int NT = K / 32;               // K-tiles of 32
    __shared__ __align__(16) unsigned short Slds[65536];   // 4 bufs x (A 16KB + B 16KB)

    const int tid  = threadIdx.x;

    // bijective XCD-aware swizzle (nwg % 8 == 0 for all our launches)
    const int gx   = gridDim.x;
    const int nwg  = gx * gridDim.y;
    const int flat = blockIdx.y * gx + blockIdx.x;
    const int swz  = (flat & 7) * (nwg >> 3) + (flat >> 3);
    const int bn   = swz % gx, bm = swz / gx;

    const int w    = tid >> 6, lane = tid & 63;
    const int wm   = (w >> 2) * 128, wn = (w & 3) * 64;   // wave tile 128x64
    const int l16  = lane & 15, quad = lane >> 4;

    // staging source addresses (pre-swizzled so linear LDS landing == swizzled layout)
    // lane covers LDS row R = 16*w + (lane>>2) [+128 for second call], slot qs = lane&3.
    // slot(R,qs) must hold k-chunk (qs ^ key(R)), key(R) = (R&3)^((R>>2)&3)
    //   => keyed by lane bits: ((lane>>2)&3) ^ ((lane>>4)&3)
    const int colblk = (((lane & 3) ^ ((lane >> 2) & 3) ^ ((lane >> 4) & 3))) * 8;
    const long arow = (long)(bm * 256 + w * 16 + (lane >> 2));
    const long brow = (long)(bn * 256 + w * 16 + (lane >> 2));
    const unsigned short* sa0 = A  + arow * K + colblk;
    const unsigned short* sa1 = sa0 + (long)128 * K;
    const unsigned short* sb0 = Bt + brow * K + colblk;
    const unsigned short* sb1 = sb0 + (long)128 * K;

    auto STAGE = [&](int tt) {
        unsigned short* db = &Slds[(tt & 3) * 16384];
        gload_lds16(sa0 + (long)tt * 32, db + w * 512);
        gload_lds16(sa1 + (long)tt * 32, db + 4096  + w * 512);
        gload_lds16(sb0 + (long)tt * 32, db + 8192  + w * 512);
        gload_lds16(sb1 + (long)tt * 32, db + 12288 + w * 512);
    };

    // ds_read swizzle: element offset within row = 8*(quad ^ key(row)); for rows
    // R = wm/wn + 16*frag + l16 (bases %16==0), key = (l16&3)^((l16>>2)&3).
    const int rq = ((quad ^ ((l16 & 3) ^ ((l16 >> 2) & 3)))) * 8;

    floatx4 acc[8][4] = {};

    STAGE(0); STAGE(1); STAGE(2);

    for (int t = 0; t < NT; ++t) {
        if (t < NT - 2)       asm volatile("s_waitcnt vmcnt(8)" ::: "memory");
        else if (t == NT - 2) asm volatile("s_waitcnt vmcnt(4)" ::: "memory");
        else                  asm volatile("s_waitcnt vmcnt(0)" ::: "memory");
        __builtin_amdgcn_s_barrier();          // tile t resident; buf (t+3)&3 free
        __builtin_amdgcn_sched_barrier(0);
        if (t + 3 < NT) STAGE(t + 3);

        const unsigned short* Ab = &Slds[(t & 3) * 16384];
        const unsigned short* Bb = Ab + 8192;
        short8 af[8], bf[4];
#pragma unroll
        for (int mi = 0; mi < 8; mi++)
            af[mi] = *(const short8*)&Ab[(wm + mi * 16 + l16) * 32 + rq];
#pragma unroll
        for (int nj = 0; nj < 4; nj++)
            bf[nj] = *(const short8*)&Bb[(wn + nj * 16 + l16) * 32 + rq];

        __builtin_amdgcn_s_setprio(1);
#pragma unroll
        for (int mi = 0; mi < 8; mi++)
#pragma unroll
            for (int nj = 0; nj < 4; nj++)
                acc[mi][nj] = __builtin_amdgcn_mfma_f32_16x16x32_bf16(af[mi], bf[nj], acc[mi][nj], 0, 0, 0);
        __builtin_amdgcn_s_setprio(0);

        __builtin_amdgcn_sched_barrier(0);     // pin ds_reads above the release fence
        asm volatile("s_waitcnt lgkmcnt(0)" ::: "memory");
        __builtin_amdgcn_s_barrier();          // all waves done reading buf t&3
    }

#pragma unroll
    for (int mi = 0; mi < 8; mi++) {
        int m0 = bm * 256 + wm + mi * 16 + quad * 4;
#pragma unroll
        for (int nj = 0; nj < 4; nj++) {
            int n = bn * 256 + wn + nj * 16 + l16;
            float bv = bias[n];
            long base = (long)m0 * N + n;
#pragma unroll
            for (int r = 0; r < 4; r++)
                store_out(C + base + (long)r * N, acc[mi][nj][r] + bv);
        }
    }
}

// ---------------- context[b,h,d,e] = sum_t exp(k[t,d]) * v[t,e] (UNNORMALIZED) ----------------
// Also accumulates S[b,d] = sum_t exp(k[t,d]). Max-shift skipped: k ~ N(0,1), far from
// f32 overflow; identical to softmax up to rounding.
__global__ __launch_bounds__(256) void context_kernel(
    const unsigned short* __restrict__ kvb,
    float* __restrict__ ctx,     // [B,H,64,64] f32, pre-zeroed
    float* __restrict__ Sbuf)    // [B,1024] f32, pre-zeroed
{
    int chunk = blockIdx.x;        // 0..7, each covers 512 t
    int h = blockIdx.y, b = blockIdx.z;
    __shared__ float Ks[16][64];
    __shared__ float Vs[16][64];
    __shared__ float Ssh[16][64];
    int tid = threadIdx.x;
    int srow = tid >> 4;
    int scol = (tid & 15) * 8;
    int td = tid & 15, te = tid >> 4;
    long colbase = (scol < 64) ? (long)(h * 64 + scol) : (long)(1024 + h * 64 + scol - 64);
    float acc[4][4] = {};
    float ssum[8] = {};

    for (int t0 = chunk * 512; t0 < (chunk + 1) * 512; t0 += 16) {
        uint4 raw = *(const uint4*)(kvb + (long)(b * T_SEQ + t0 + srow) * 2048 + colbase);
        unsigned short u[8];
        *(uint4*)u = raw;
        if (scol < 64) {
#pragma unroll
            for (int j = 0; j < 8; j++) {
                float e = __expf(b2f(u[j]));
                Ks[srow][scol + j] = e;
                ssum[j] += e;
            }
        } else {
#pragma unroll
            for (int j = 0; j < 8; j++)
                Vs[srow][scol - 64 + j] = b2f(u[j]);
        }
        __syncthreads();
#pragma unroll
        for (int t = 0; t < 16; t++) {
            float k4[4], v4[4];
#pragma unroll
            for (int i = 0; i < 4; i++) k4[i] = Ks[t][td * 4 + i];
#pragma unroll
            for (int j = 0; j < 4; j++) v4[j] = Vs[t][te * 4 + j];
#pragma unroll
            for (int i = 0; i < 4; i++)
#pragma unroll
                for (int j = 0; j < 4; j++) acc[i][j] = fmaf(k4[i], v4[j], acc[i][j]);
        }
        __syncthreads();
    }

    if (scol < 64) {
#pragma unroll
        for (int j = 0; j < 8; j++) Ssh[srow][scol + j] = ssum[j];
    }
    __syncthreads();
    if (tid < 64) {
        float s = 0.f;
#pragma unroll
        for (int r = 0; r < 16; r++) s += Ssh[r][tid];
        atomicAdd(&Sbuf[b * 1024 + h * 64 + tid], s);
    }

    float* cb = ctx + (long)(b * NH + h) * 4096;
#pragma unroll
    for (int i = 0; i < 4; i++)
#pragma unroll
        for (int j = 0; j < 4; j++)
            atomicAdd(&cb[(td * 4 + i) * 64 + te * 4 + j], acc[i][j]);
}

// ---------------- finalize: ctxb[b,h,e,d] = bf16( ctx[b,h,d,e] / S[b,h*64+d] ) ----------------
__global__ __launch_bounds__(256) void finalize_ctx(
    const float* __restrict__ ctx, const float* __restrict__ Sbuf,
    unsigned short* __restrict__ ctxb)
{
    int bh = blockIdx.x;           // 0..63  (b*16+h)
    int b = bh >> 4, h = bh & 15;
    const float* cb = ctx + (long)bh * 4096;
    const float* Sb = Sbuf + b * 1024 + h * 64;
    unsigned short* ob = ctxb + (long)bh * 4096;
    int tid = threadIdx.x;
    int e = tid >> 2, d0 = (tid & 3) * 16;
    unsigned short u[16];
#pragma unroll
    for (int j = 0; j < 16; j++) {
        int d = d0 + j;
        u[j] = f2b(cb[d * 64 + e] * (1.0f / Sb[d]));
    }
    *(uint4*)(ob + e * 64 + d0)     = *(uint4*)u;
    *(uint4*)(ob + e * 64 + d0 + 8) = *((uint4*)u + 1);
}

// ---------------- attn via MFMA: qb[t, h*64+e] = sum_d qb[t,h*64+d] * ctxb[b,h,e,d] ----------------
__global__ __launch_bounds__(256) void attn_mfma(
    unsigned short* __restrict__ qb,            // [16384,1024] bf16, in/out
    const unsigned short* __restrict__ ctxb)    // [B,H,64(e),64(d)] bf16 normalized
{
    int tc = blockIdx.x, h = blockIdx.y, b = blockIdx.z;
    int w = threadIdx.x >> 6, lane = threadIdx.x & 63;
    int l16 = lane & 15, quad = lane >> 4;

    const unsigned short* cb = ctxb + (long)(b * NH + h) * 4096;
    short8 bf[4][2];
#pragma unroll
    for (int j = 0; j < 4; j++)
#pragma unroll
        for (int ks = 0; ks < 2; ks++)
            bf[j][ks] = *(const short8*)(cb + (j * 16 + l16) * 64 + ks * 32 + quad * 8);

    long trow0 = (long)b * T_SEQ + tc * 256 + w * 64;
    unsigned short* qrow = qb + trow0 * 1024 + h * 64;

    short8 af[4][2];
#pragma unroll
    for (int i = 0; i < 4; i++)
#pragma unroll
        for (int ks = 0; ks < 2; ks++)
            af[i][ks] = *(const short8*)(qrow + (long)(i * 16 + l16) * 1024 + ks * 32 + quad * 8);

    floatx4 acc[4][4] = {};
#pragma unroll
    for (int i = 0; i < 4; i++)
#pragma unroll
        for (int j = 0; j < 4; j++) {
            acc[i][j] = __builtin_amdgcn_mfma_f32_16x16x32_bf16(af[i][0], bf[j][0], acc[i][j], 0, 0, 0);
            acc[i][j] = __builtin_amdgcn_mfma_f32_16x16x32_bf16(af[i][1], bf[j][1], acc[i][j], 0, 0, 0);
        }

#pragma unroll
    for (int i = 0; i < 4; i++)
#pragma unroll
        for (int j = 0; j < 4; j++)
#pragma unroll
            for (int r = 0; r < 4; r++)
                qrow[(long)(i * 16 + quad * 4 + r) * 1024 + j * 16 + l16] = f2b(acc[i][j][r]);
}

// ---------------- launch ----------------
extern "C" void kernel_launch(void* const* d_in, const int* in_sizes, int n_in,
                              void* d_out, int out_size, void* d_ws, size_t ws_size,
                              hipStream_t stream) {
    const float* x     = (const float*)d_in[0];
    const float* z     = (const float*)d_in[1];
    const float* w_q   = (const float*)d_in[2];
    const float* b_q   = (const float*)d_in[3];
    const float* w_kv  = (const float*)d_in[4];
    const float* b_kv  = (const float*)d_in[5];
    const float* w_out = (const float*)d_in[6];
    const float* b_out = (const float*)d_in[7];
    float* out = (float*)d_out;            // reference output dtype is float32

    char* ws = (char*)d_ws;
    unsigned short* kvb   = (unsigned short*)(ws);                  // [16384,2048] bf16 = 64 MB
    unsigned short* qb    = (unsigned short*)(ws + 67108864);       // [16384,1024] bf16 = 32 MB
    unsigned short* wqT   = (unsigned short*)(ws + 100663296);      // 2 MB
    unsigned short* wkvT  = (unsigned short*)(ws + 102760448);      // 4 MB
    unsigned short* woutT = (unsigned short*)(ws + 106954752);      // 2 MB
    float* Sbuf  = (float*)(ws + 109051904);                        // 16 KB
    float* ctx   = (float*)(ws + 109084672);                        // 1 MB
    unsigned short* ctxb = (unsigned short*)(ws + 110133248);       // 512 KB  (peak ~105.5 MiB)

    // xb/zb (bf16 copies of x,z) live inside d_out: dead once q/kv GEMMs complete,
    // and d_out is only written by the final GEMM.
    unsigned short* xb = (unsigned short*)d_out;
    unsigned short* zb = (unsigned short*)((char*)d_out + 33554432);

    hipMemsetAsync(ctx, 0, (size_t)BATCH * NH * 64 * 64 * 4, stream);
    hipMemsetAsync(Sbuf, 0, (size_t)BATCH * 1024 * 4, stream);
    convert_bf16<<<dim3(8192, 2), 256, 0, stream>>>(x, z, xb, zb);
    transpose_w<<<4096, 256, 0, stream>>>(w_q, w_kv, w_out, wqT, wkvT, woutT);
    // q = x @ w_q + b_q   [16384,1024] bf16
    gemm_bt<1024, unsigned short><<<dim3(4, 64), WGS, 0, stream>>>(xb, wqT, b_q, qb, 1024);
    // kv = z @ w_kv + b_kv   [16384,2048] bf16
    gemm_bt<1024, unsigned short><<<dim3(8, 64), WGS, 0, stream>>>(zb, wkvT, b_kv, kvb, 2048);
    // fused: unnormalized context + denominator S
    context_kernel<<<dim3(8, NH, BATCH), 256, 0, stream>>>(kvb, ctx, Sbuf);
    // normalize + transpose ctx to bf16 Bt layout
    finalize_ctx<<<64, 256, 0, stream>>>(ctx, Sbuf, ctxb);
    // attn: q <- q @ ctx^T (per head), in place, MFMA
    attn_mfma<<<dim3(T_SEQ / 256, NH, BATCH), 256, 0, stream>>>(qb, ctxb);
    // out = attn @ w_out + b_out   [16384,1024] f32 -> d_out
    gemm_bt<1024, float><<<dim3(4, 64), WGS, 0, stream>>>(qb, woutT, b_out, out, 1024);
}

// Round 5
// 411.974 us; speedup vs baseline: 2.2701x; 1.0372x over previous
//
#include <hip/hip_runtime.h>

// ---------------- problem constants ----------------
#define T_SEQ 4096
#define BATCH 4
#define NH 16
#define M_ROWS 16384

typedef __attribute__((ext_vector_type(8))) short short8;
typedef __attribute__((ext_vector_type(4))) float floatx4;

__device__ __forceinline__ float b2f(unsigned short u) {
    union { unsigned int i; float f; } x; x.i = ((unsigned int)u) << 16; return x.f;
}
__device__ __forceinline__ unsigned short f2b(float f) {
    union { float f; unsigned int i; } x; x.f = f;
    unsigned int u = x.i;
    u += 0x7fffu + ((u >> 16) & 1u);   // RNE
    return (unsigned short)(u >> 16);
}

__device__ __forceinline__ void store_out(float* p, float v) { *p = v; }
__device__ __forceinline__ void store_out(unsigned short* p, float v) { *p = f2b(v); }

// async global->LDS, 16B per lane; LDS dest is wave-uniform base (+lane*16 implicit)
__device__ __forceinline__ void gload_lds16(const unsigned short* g, unsigned short* l) {
    __builtin_amdgcn_global_load_lds(
        (const __attribute__((address_space(1))) void*)g,
        (__attribute__((address_space(3))) void*)l, 16, 0, 0);
}

// ---------------- f32 -> bf16 bulk convert: x,z -> xb,zb ----------------
__global__ __launch_bounds__(256) void convert_bf16(
    const float* __restrict__ x, const float* __restrict__ z,
    unsigned short* __restrict__ xb, unsigned short* __restrict__ zb)
{
    const float* s      = blockIdx.y ? z : x;
    unsigned short* d   = blockIdx.y ? zb : xb;
    long i = ((long)blockIdx.x * 256 + threadIdx.x) * 8;
    float4 f0 = *(const float4*)(s + i);
    float4 f1 = *(const float4*)(s + i + 4);
    unsigned short u[8];
    u[0] = f2b(f0.x); u[1] = f2b(f0.y); u[2] = f2b(f0.z); u[3] = f2b(f0.w);
    u[4] = f2b(f1.x); u[5] = f2b(f1.y); u[6] = f2b(f1.z); u[7] = f2b(f1.w);
    *(uint4*)(d + i) = *(uint4*)u;
}

// ---------------- weight transpose+convert: W[K][N] f32 -> Wt[N][K] bf16 ----------------
__global__ __launch_bounds__(256) void transpose_w(
    const float* __restrict__ wq,
    const float* __restrict__ wkv,
    const float* __restrict__ wout,
    unsigned short* __restrict__ wqT,
    unsigned short* __restrict__ wkvT,
    unsigned short* __restrict__ woutT)
{
    int bid = blockIdx.x;
    const float* src; unsigned short* dst; int Nd; int local;
    if (bid < 1024)      { src = wq;   dst = wqT;   Nd = 1024; local = bid; }
    else if (bid < 3072) { src = wkv;  dst = wkvT;  Nd = 2048; local = bid - 1024; }
    else                 { src = wout; dst = woutT; Nd = 1024; local = bid - 3072; }
    int tilesN = Nd >> 5;
    int tk = local / tilesN, tn = local % tilesN;
    __shared__ __align__(16) unsigned short tile[32][36];
    int tid = threadIdx.x;
    int r = tid >> 3, c = (tid & 7) * 4;
    float4 in = *(const float4*)(src + (long)(tk * 32 + r) * Nd + tn * 32 + c);
    tile[r][c] = f2b(in.x); tile[r][c + 1] = f2b(in.y);
    tile[r][c + 2] = f2b(in.z); tile[r][c + 3] = f2b(in.w);
    __syncthreads();
    ushort4 o;
    o.x = tile[c][r]; o.y = tile[c + 1][r]; o.z = tile[c + 2][r]; o.w = tile[c + 3][r];
    *(ushort4*)(dst + (long)(tn * 32 + r) * 1024 + tk * 32 + c) = o;
}

// ---------------- 8-phase-style deep-pipelined bf16 MFMA GEMM ----------------
// C[M,N] = A[M,K]*Bt[N,K]^T + bias. 256x256 tile, BK=64, 8 waves (2M x 4N),
// 2 LDS buffers (128 KiB), 4 phases per K-tile each {ds_read subtile | stage ->
// barrier -> lgkmcnt(0) -> setprio -> 16 MFMA -> barrier}. K-tile kt+1 staged into
// the buffer freed at kt-1; one vmcnt(0) per K-tile (loads >= 2 phases old: free).
// 3-bit XOR bank swizzle (blk ^= row&7) applied BOTH sides: inverse-permuted global
// source for global_load_lds (linear LDS landing) + swizzled ds_read column.
#define WGS 512

template <int K, typename OT>
__global__ __launch_bounds__(WGS, 2) void gemm_bt(
    const unsigned short* __restrict__ A,    // [M,K] bf16 row-major
    const unsigned short* __restrict__ Bt,   // [N,K] bf16 row-major (B transposed)
    const float* __restrict__ bias,          // [N] f32
    OT* __restrict__ C,                      // [M,N]
    int N)
{
    constexpr int NT = K / 64;
    // layout (elems): buf d at d*32768; A-half h at +h*8192; B at +16384, half h +h*8192
    __shared__ __align__(16) unsigned short Slds[65536];   // 128 KiB

    const int tid  = threadIdx.x;

    // bijective XCD-aware swizzle (nwg % 8 == 0 for all our launches)
    const int gx   = gridDim.x;
    const int nwg  = gx * gridDim.y;
    const int flat = blockIdx.y * gx + blockIdx.x;
    const int swz  = (flat & 7) * (nwg >> 3) + (flat >> 3);
    const int bn   = swz % gx, bm = swz / gx;

    const int w    = tid >> 6, lane = tid & 63;
    const int l16  = lane & 15, quad = lane >> 4;
    const int wm   = (w >> 2) * 128, wn = (w & 3) * 64;   // wave tile 128x64

    // staging source (pre-swizzled): lane covers half-row c*64 + w*8 + (lane>>3),
    // physical col-block lane&7 must hold global col-block (lane&7) ^ (row&7),
    // row&7 == lane>>3 here.
    const int srowoff = w * 8 + (lane >> 3);
    const int scol    = ((lane & 7) ^ (lane >> 3)) * 8;
    const unsigned short* paS = A  + (long)(bm * 256 + srowoff) * K + scol;
    const unsigned short* pbS = Bt + (long)(bn * 256 + srowoff) * K + scol;
    const int ldsW = w * 512;                 // wave-uniform staging dest (elems)

    // ds_read bases; csw = row&7 swizzle key (row = ...16*frag + l16)
    const int aOff = (w >> 2) * 8192;
    const int bOff = 16384 + ((w & 3) >> 1) * 8192 + (w & 1) * 4096;
    const int csw  = l16 & 7;

    short8 af[2][4][2], bf[2][2][2];
    floatx4 acc[8][4] = {};

    auto STG_A = [&](int dn, int kt1) {      // stage both A-halves of K-tile kt1
        const unsigned short* s = paS + (long)kt1 * 64;
        unsigned short* l = &Slds[dn * 32768 + ldsW];
        gload_lds16(s,                 l);            // h0,c0
        gload_lds16(s + (long)64 * K,  l + 4096);     // h0,c1
        gload_lds16(s + (long)128 * K, l + 8192);     // h1,c0
        gload_lds16(s + (long)192 * K, l + 12288);    // h1,c1
    };
    auto STG_B = [&](int dn, int kt1) {
        const unsigned short* s = pbS + (long)kt1 * 64;
        unsigned short* l = &Slds[dn * 32768 + 16384 + ldsW];
        gload_lds16(s,                 l);
        gload_lds16(s + (long)64 * K,  l + 4096);
        gload_lds16(s + (long)128 * K, l + 8192);
        gload_lds16(s + (long)192 * K, l + 12288);
    };
    auto LDA = [&](int d, int ab, int mi, int ks) {
        af[ab][mi][ks] = *(const short8*)&Slds[d * 32768 + aOff
            + (ab * 64 + mi * 16 + l16) * 64 + ((((ks << 2) | quad) ^ csw) << 3)];
    };
    auto LDB = [&](int d, int bb, int nj, int ks) {
        bf[bb][nj][ks] = *(const short8*)&Slds[d * 32768 + bOff
            + (bb * 32 + nj * 16 + l16) * 64 + ((((ks << 2) | quad) ^ csw) << 3)];
    };
    auto MMQ = [&](int ab, int bb) {
#pragma unroll
        for (int mi = 0; mi < 4; ++mi)
#pragma unroll
            for (int nj = 0; nj < 2; ++nj)
#pragma unroll
                for (int ks = 0; ks < 2; ++ks)
                    acc[ab * 4 + mi][bb * 2 + nj] =
                        __builtin_amdgcn_mfma_f32_16x16x32_bf16(
                            af[ab][mi][ks], bf[bb][nj][ks],
                            acc[ab * 4 + mi][bb * 2 + nj], 0, 0, 0);
    };

    // prologue: stage K-tile 0 into buf 0, drain, sync
    STG_A(0, 0); STG_B(0, 0);
    asm volatile("s_waitcnt vmcnt(0)" ::: "memory");
    __builtin_amdgcn_s_barrier();

    for (int kt = 0; kt < NT; ++kt) {
        const int d = kt & 1, dn = d ^ 1;
        // ---- phase 1: read af bank0 (8) + bf bank0 (4); stage next A-halves ----
#pragma unroll
        for (int mi = 0; mi < 4; ++mi) { LDA(d, 0, mi, 0); LDA(d, 0, mi, 1); }
#pragma unroll
        for (int nj = 0; nj < 2; ++nj) { LDB(d, 0, nj, 0); LDB(d, 0, nj, 1); }
        if (kt + 1 < NT) STG_A(dn, kt + 1);
        __builtin_amdgcn_s_barrier();
        asm volatile("s_waitcnt lgkmcnt(0)" ::: "memory");
        __builtin_amdgcn_sched_barrier(0);
        __builtin_amdgcn_s_setprio(1);
        MMQ(0, 0);
        __builtin_amdgcn_s_setprio(0);
        __builtin_amdgcn_s_barrier();
        // ---- phase 2: read af bank1 (8); stage next B-halves ----
#pragma unroll
        for (int mi = 0; mi < 4; ++mi) { LDA(d, 1, mi, 0); LDA(d, 1, mi, 1); }
        if (kt + 1 < NT) STG_B(dn, kt + 1);
        __builtin_amdgcn_s_barrier();
        asm volatile("s_waitcnt lgkmcnt(0)" ::: "memory");
        __builtin_amdgcn_sched_barrier(0);
        __builtin_amdgcn_s_setprio(1);
        MMQ(1, 0);
        __builtin_amdgcn_s_setprio(0);
        __builtin_amdgcn_s_barrier();
        // ---- phase 3: read bf bank1 (4) ----
#pragma unroll
        for (int nj = 0; nj < 2; ++nj) { LDB(d, 1, nj, 0); LDB(d, 1, nj, 1); }
        __builtin_amdgcn_s_barrier();
        asm volatile("s_waitcnt lgkmcnt(0)" ::: "memory");
        __builtin_amdgcn_sched_barrier(0);
        __builtin_amdgcn_s_setprio(1);
        MMQ(0, 1);
        __builtin_amdgcn_s_setprio(0);
        __builtin_amdgcn_s_barrier();
        // ---- phase 4: drain next-tile stages (issued >= 2 phases ago); MFMA Q11 ----
        asm volatile("s_waitcnt vmcnt(0)" ::: "memory");
        __builtin_amdgcn_s_barrier();
        __builtin_amdgcn_s_setprio(1);
        MMQ(1, 1);
        __builtin_amdgcn_s_setprio(0);
        __builtin_amdgcn_s_barrier();
    }

#pragma unroll
    for (int mi = 0; mi < 8; ++mi) {
        int m0 = bm * 256 + wm + mi * 16 + quad * 4;
#pragma unroll
        for (int nj = 0; nj < 4; ++nj) {
            int n = bn * 256 + wn + nj * 16 + l16;
            float bv = bias[n];
            long base = (long)m0 * N + n;
#pragma unroll
            for (int r = 0; r < 4; ++r)
                store_out(C + base + (long)r * N, acc[mi][nj][r] + bv);
        }
    }
}

// ---------------- context[b,h,d,e] = sum_t exp(k[t,d]) * v[t,e] (UNNORMALIZED) ----------------
// Also accumulates S[b,d] = sum_t exp(k[t,d]). Max-shift skipped: k ~ N(0,1), far from
// f32 overflow; identical to softmax up to rounding.
__global__ __launch_bounds__(256) void context_kernel(
    const unsigned short* __restrict__ kvb,
    float* __restrict__ ctx,     // [B,H,64,64] f32, pre-zeroed
    float* __restrict__ Sbuf)    // [B,1024] f32, pre-zeroed
{
    int chunk = blockIdx.x;        // 0..7, each covers 512 t
    int h = blockIdx.y, b = blockIdx.z;
    __shared__ float Ks[16][64];
    __shared__ float Vs[16][64];
    __shared__ float Ssh[16][64];
    int tid = threadIdx.x;
    int srow = tid >> 4;
    int scol = (tid & 15) * 8;
    int td = tid & 15, te = tid >> 4;
    long colbase = (scol < 64) ? (long)(h * 64 + scol) : (long)(1024 + h * 64 + scol - 64);
    float acc[4][4] = {};
    float ssum[8] = {};

    for (int t0 = chunk * 512; t0 < (chunk + 1) * 512; t0 += 16) {
        uint4 raw = *(const uint4*)(kvb + (long)(b * T_SEQ + t0 + srow) * 2048 + colbase);
        unsigned short u[8];
        *(uint4*)u = raw;
        if (scol < 64) {
#pragma unroll
            for (int j = 0; j < 8; j++) {
                float e = __expf(b2f(u[j]));
                Ks[srow][scol + j] = e;
                ssum[j] += e;
            }
        } else {
#pragma unroll
            for (int j = 0; j < 8; j++)
                Vs[srow][scol - 64 + j] = b2f(u[j]);
        }
        __syncthreads();
#pragma unroll
        for (int t = 0; t < 16; t++) {
            float k4[4], v4[4];
#pragma unroll
            for (int i = 0; i < 4; i++) k4[i] = Ks[t][td * 4 + i];
#pragma unroll
            for (int j = 0; j < 4; j++) v4[j] = Vs[t][te * 4 + j];
#pragma unroll
            for (int i = 0; i < 4; i++)
#pragma unroll
                for (int j = 0; j < 4; j++) acc[i][j] = fmaf(k4[i], v4[j], acc[i][j]);
        }
        __syncthreads();
    }

    if (scol < 64) {
#pragma unroll
        for (int j = 0; j < 8; j++) Ssh[srow][scol + j] = ssum[j];
    }
    __syncthreads();
    if (tid < 64) {
        float s = 0.f;
#pragma unroll
        for (int r = 0; r < 16; r++) s += Ssh[r][tid];
        atomicAdd(&Sbuf[b * 1024 + h * 64 + tid], s);
    }

    float* cb = ctx + (long)(b * NH + h) * 4096;
#pragma unroll
    for (int i = 0; i < 4; i++)
#pragma unroll
        for (int j = 0; j < 4; j++)
            atomicAdd(&cb[(td * 4 + i) * 64 + te * 4 + j], acc[i][j]);
}

// ---------------- finalize: ctxb[b,h,e,d] = bf16( ctx[b,h,d,e] / S[b,h*64+d] ) ----------------
__global__ __launch_bounds__(256) void finalize_ctx(
    const float* __restrict__ ctx, const float* __restrict__ Sbuf,
    unsigned short* __restrict__ ctxb)
{
    int bh = blockIdx.x;           // 0..63  (b*16+h)
    int b = bh >> 4, h = bh & 15;
    const float* cb = ctx + (long)bh * 4096;
    const float* Sb = Sbuf + b * 1024 + h * 64;
    unsigned short* ob = ctxb + (long)bh * 4096;
    int tid = threadIdx.x;
    int e = tid >> 2, d0 = (tid & 3) * 16;
    unsigned short u[16];
#pragma unroll
    for (int j = 0; j < 16; j++) {
        int d = d0 + j;
        u[j] = f2b(cb[d * 64 + e] * (1.0f / Sb[d]));
    }
    *(uint4*)(ob + e * 64 + d0)     = *(uint4*)u;
    *(uint4*)(ob + e * 64 + d0 + 8) = *((uint4*)u + 1);
}

// ---------------- attn via MFMA: qb[t, h*64+e] = sum_d qb[t,h*64+d] * ctxb[b,h,e,d] ----------------
__global__ __launch_bounds__(256) void attn_mfma(
    unsigned short* __restrict__ qb,            // [16384,1024] bf16, in/out
    const unsigned short* __restrict__ ctxb)    // [B,H,64(e),64(d)] bf16 normalized
{
    int tc = blockIdx.x, h = blockIdx.y, b = blockIdx.z;
    int w = threadIdx.x >> 6, lane = threadIdx.x & 63;
    int l16 = lane & 15, quad = lane >> 4;

    const unsigned short* cb = ctxb + (long)(b * NH + h) * 4096;
    short8 bf[4][2];
#pragma unroll
    for (int j = 0; j < 4; j++)
#pragma unroll
        for (int ks = 0; ks < 2; ks++)
            bf[j][ks] = *(const short8*)(cb + (j * 16 + l16) * 64 + ks * 32 + quad * 8);

    long trow0 = (long)b * T_SEQ + tc * 256 + w * 64;
    unsigned short* qrow = qb + trow0 * 1024 + h * 64;

    short8 af[4][2];
#pragma unroll
    for (int i = 0; i < 4; i++)
#pragma unroll
        for (int ks = 0; ks < 2; ks++)
            af[i][ks] = *(const short8*)(qrow + (long)(i * 16 + l16) * 1024 + ks * 32 + quad * 8);

    floatx4 acc[4][4] = {};
#pragma unroll
    for (int i = 0; i < 4; i++)
#pragma unroll
        for (int j = 0; j < 4; j++) {
            acc[i][j] = __builtin_amdgcn_mfma_f32_16x16x32_bf16(af[i][0], bf[j][0], acc[i][j], 0, 0, 0);
            acc[i][j] = __builtin_amdgcn_mfma_f32_16x16x32_bf16(af[i][1], bf[j][1], acc[i][j], 0, 0, 0);
        }

#pragma unroll
    for (int i = 0; i < 4; i++)
#pragma unroll
        for (int j = 0; j < 4; j++)
#pragma unroll
            for (int r = 0; r < 4; r++)
                qrow[(long)(i * 16 + quad * 4 + r) * 1024 + j * 16 + l16] = f2b(acc[i][j][r]);
}

// ---------------- launch ----------------
extern "C" void kernel_launch(void* const* d_in, const int* in_sizes, int n_in,
                              void* d_out, int out_size, void* d_ws, size_t ws_size,
                              hipStream_t stream) {
    const float* x     = (const float*)d_in[0];
    const float* z     = (const float*)d_in[1];
    const float* w_q   = (const float*)d_in[2];
    const float* b_q   = (const float*)d_in[3];
    const float* w_kv  = (const float*)d_in[4];
    const float* b_kv  = (const float*)d_in[5];
    const float* w_out = (const float*)d_in[6];
    const float* b_out = (const float*)d_in[7];
    float* out = (float*)d_out;            // reference output dtype is float32

    char* ws = (char*)d_ws;
    unsigned short* kvb   = (unsigned short*)(ws);                  // [16384,2048] bf16 = 64 MB
    unsigned short* qb    = (unsigned short*)(ws + 67108864);       // [16384,1024] bf16 = 32 MB
    unsigned short* wqT   = (unsigned short*)(ws + 100663296);      // 2 MB
    unsigned short* wkvT  = (unsigned short*)(ws + 102760448);      // 4 MB
    unsigned short* woutT = (unsigned short*)(ws + 106954752);      // 2 MB
    float* Sbuf  = (float*)(ws + 109051904);                        // 16 KB
    float* ctx   = (float*)(ws + 109084672);                        // 1 MB
    unsigned short* ctxb = (unsigned short*)(ws + 110133248);       // 512 KB  (peak ~105.5 MiB)

    // xb/zb (bf16 copies of x,z) live inside d_out: dead once q/kv GEMMs complete,
    // and d_out is only written by the final GEMM.
    unsigned short* xb = (unsigned short*)d_out;
    unsigned short* zb = (unsigned short*)((char*)d_out + 33554432);

    hipMemsetAsync(ctx, 0, (size_t)BATCH * NH * 64 * 64 * 4, stream);
    hipMemsetAsync(Sbuf, 0, (size_t)BATCH * 1024 * 4, stream);
    convert_bf16<<<dim3(8192, 2), 256, 0, stream>>>(x, z, xb, zb);
    transpose_w<<<4096, 256, 0, stream>>>(w_q, w_kv, w_out, wqT, wkvT, woutT);
    // q = x @ w_q + b_q   [16384,1024] bf16
    gemm_bt<1024, unsigned short><<<dim3(4, 64), WGS, 0, stream>>>(xb, wqT, b_q, qb, 1024);
    // kv = z @ w_kv + b_kv   [16384,2048] bf16
    gemm_bt<1024, unsigned short><<<dim3(8, 64), WGS, 0, stream>>>(zb, wkvT, b_kv, kvb, 2048);
    // fused: unnormalized context + denominator S
    context_kernel<<<dim3(8, NH, BATCH), 256, 0, stream>>>(kvb, ctx, Sbuf);
    // normalize + transpose ctx to bf16 Bt layout
    finalize_ctx<<<64, 256, 0, stream>>>(ctx, Sbuf, ctxb);
    // attn: q <- q @ ctx^T (per head), in place, MFMA
    attn_mfma<<<dim3(T_SEQ / 256, NH, BATCH), 256, 0, stream>>>(qb, ctxb);
    // out = attn @ w_out + b_out   [16384,1024] f32 -> d_out
    gemm_bt<1024, float><<<dim3(4, 64), WGS, 0, stream>>>(qb, woutT, b_out, out, 1024);
}